// Round 2
// baseline (675.478 us; speedup 1.0000x reference)
//
#include <hip/hip_runtime.h>
#include <cstdint>

// DifferentiableStarPlanner, MI355X.
// Key insights:
//  - open_/close in the reference scan are dead code w.r.t. the returned g.
//  - All neighbor costs are > 0 => g propagates <= 1 cell (Chebyshev) per step.
//    Cells farther than num_steps from every start cell keep g_init EXACTLY.
//  - So: init g everywhere (grid kernel), find start bbox via atomics, then run
//    all 64 min-plus relaxation steps on the (bbox +- num_steps) region inside
//    ONE persistent 1024-thread workgroup, double-buffered in LDS.
//  - Per-cell 8-direction costs are constant across steps: precomputed into
//    registers (5x4 cells/thread, fully unrolled -> static indexing, no scratch).
//  - Note reference quirk: the W-neighbor channel uses the N obstacle (obst(-1,0)).

#define HH 1024
#define WW 1024
#define FINF 1.0e7f
#define FOB  1.0e4f
#define FEPS 1e-12f
#define BIGC 1.0e30f     // cost for non-existent cells: keeps their g at FINF

#define MAXR 132         // max supported region edge (actual: 1 + 2*64 = 129)
#define LDW  140         // LDS row stride (floats): region col c -> LDS col c+4 (b128-aligned)
#define LDH  138         // LDS rows: region row r -> LDS row r+1; covers strip overreach
#define SR   5           // strip rows per thread
#define SC   4           // strip cols per thread (=> float4/ds_read_b128 granularity)
#define SCOLS 33         // MAXR/SC
#define SROWS 27         // ceil(MAXR/SR) -> 891 active threads of 1024

// -------- per-cell, per-direction path costs (exact port of calculateLocalPathCosts)
__device__ __forceinline__ void cost8(const float* __restrict__ ob,
                                      const float* __restrict__ yco,
                                      const float* __restrict__ xco,
                                      int gi, int gj, float c[8])
{
  const int jm = gj > 0      ? gj - 1 : 0;
  const int jp = gj < WW - 1 ? gj + 1 : WW - 1;
  const int im = gi > 0      ? gi - 1 : 0;
  const int ip = gi < HH - 1 ? gi + 1 : HH - 1;
  const float xc = xco[gi * WW + gj];
  const float yc = yco[gi * WW + gj];
  const float dl = xc - xco[gi * WW + jm]; const float l = dl * dl;   // left
  const float dr = xc - xco[gi * WW + jp]; const float r = dr * dr;   // right
  const float du = yc - yco[im * WW + gj]; const float u = du * du;   // up
  const float dd = yc - yco[ip * WW + gj]; const float d = dd * dd;   // down
  const float oc  = ob[gi * WW + gj];
  const float oNW = ob[im * WW + jm], oN = ob[im * WW + gj], oNE = ob[im * WW + jp];
  const float oE  = ob[gi * WW + jp];
  const float oSW = ob[ip * WW + jm], oS = ob[ip * WW + gj], oSE = ob[ip * WW + jp];
  // dir order: 0 NW(-1,-1) 1 W(0,-1) 2 SW(1,-1) 3 N(-1,0) 4 S(1,0) 5 NE(-1,1) 6 E(0,1) 7 SE(1,1)
  c[0] = sqrtf(l + u + FEPS) + FOB * fmaxf(oNW, oc);
  c[1] = sqrtf(l + FEPS)     + FOB * fmaxf(oN , oc);  // reference quirk: uses N obstacle
  c[2] = sqrtf(l + d + FEPS) + FOB * fmaxf(oSW, oc);
  c[3] = sqrtf(u + FEPS)     + FOB * fmaxf(oN , oc);
  c[4] = sqrtf(d + FEPS)     + FOB * fmaxf(oS , oc);
  c[5] = sqrtf(r + u + FEPS) + FOB * fmaxf(oNE, oc);
  c[6] = sqrtf(r + FEPS)     + FOB * fmaxf(oE , oc);
  c[7] = sqrtf(r + d + FEPS) + FOB * fmaxf(oSE, oc);
}

// -------- K0: init bbox words (ws is poisoned 0xAA each call; don't rely on it)
__global__ void k_bbinit(unsigned int* bb)
{
  if (threadIdx.x < 4) bb[threadIdx.x] = 0xFFFFFFFFu;
}

// -------- KA: g_init over the whole image + start-cell bbox via uint atomicMin
// bbox encoding (all atomicMin): bb0=min r, bb1=min(4096-r), bb2=min c, bb3=min(4096-c)
__global__ void k_init(const float* __restrict__ start, float* __restrict__ g,
                       unsigned int* bb)
{
  const int idx = blockIdx.x * blockDim.x + threadIdx.x;     // over H*W/4
  const float4 s = reinterpret_cast<const float4*>(start)[idx];
  float4 o;
  o.x = fminf(fmaxf(FINF * (1.0f - s.x), 0.0f), FINF);
  o.y = fminf(fmaxf(FINF * (1.0f - s.y), 0.0f), FINF);
  o.z = fminf(fmaxf(FINF * (1.0f - s.z), 0.0f), FINF);
  o.w = fminf(fmaxf(FINF * (1.0f - s.w), 0.0f), FINF);
  reinterpret_cast<float4*>(g)[idx] = o;
  if (s.x > 0.0f || s.y > 0.0f || s.z > 0.0f || s.w > 0.0f) {
    const int base = idx * 4;
    const int r  = base >> 10;          // /WW
    const int c0 = base & (WW - 1);
    atomicMin(bb + 0, (unsigned)r);
    atomicMin(bb + 1, (unsigned)(4096 - r));
    if (s.x > 0.0f) { atomicMin(bb + 2, (unsigned)(c0 + 0)); atomicMin(bb + 3, (unsigned)(4096 - (c0 + 0))); }
    if (s.y > 0.0f) { atomicMin(bb + 2, (unsigned)(c0 + 1)); atomicMin(bb + 3, (unsigned)(4096 - (c0 + 1))); }
    if (s.z > 0.0f) { atomicMin(bb + 2, (unsigned)(c0 + 2)); atomicMin(bb + 3, (unsigned)(4096 - (c0 + 2))); }
    if (s.w > 0.0f) { atomicMin(bb + 2, (unsigned)(c0 + 3)); atomicMin(bb + 3, (unsigned)(4096 - (c0 + 3))); }
  }
}

// -------- KB: persistent single-workgroup region iteration
__global__ __launch_bounds__(1024) void k_iter(
    const float* __restrict__ ob, const float* __restrict__ co,
    const float* __restrict__ start, const unsigned int* __restrict__ bb,
    float* __restrict__ g, const int* __restrict__ nsp,
    float* wsg, int ws_ok)
{
  __shared__ float L[2][LDH * LDW];
  const float* yco = co;               // coords ch0 = y
  const float* xco = co + HH * WW;     // coords ch1 = x
  const int tid = threadIdx.x;
  int ns = *nsp; if (ns < 0) ns = 0;

  if (bb[0] > (unsigned)(HH - 1)) return;   // no start cells: g stays g_init. correct.
  const int i0 = (int)bb[0], i1 = 4096 - (int)bb[1];
  const int j0 = (int)bb[2], j1 = 4096 - (int)bb[3];
  int ri0 = i0 - ns; if (ri0 < 0) ri0 = 0;
  int ri1 = i1 + ns; if (ri1 > HH - 1) ri1 = HH - 1;
  int rj0 = j0 - ns; if (rj0 < 0) rj0 = 0;
  int rj1 = j1 + ns; if (rj1 > WW - 1) rj1 = WW - 1;
  const int RH = ri1 - ri0 + 1, RW = rj1 - rj0 + 1;

  if (RH > MAXR || RW > MAXR) {
    // Defensive fallback (unreachable with harness inputs: region = 129x129).
    // Slow but correct global Jacobi, single workgroup, ping-pong g <-> wsg.
    if (!ws_ok) return;
    for (int s = 0; s < ns; ++s) {
      const float* src = (s & 1) ? wsg : g;
      float*       dst = (s & 1) ? g : wsg;
      for (int k = tid; k < HH * WW; k += 1024) {
        const int gi = k >> 10, gj = k & (WW - 1);
        float c[8]; cost8(ob, yco, xco, gi, gj, c);
        const int im = gi > 0 ? gi - 1 : 0, ip = gi < HH - 1 ? gi + 1 : HH - 1;
        const int jm = gj > 0 ? gj - 1 : 0, jp = gj < WW - 1 ? gj + 1 : WW - 1;
        float m = src[k];
        m = fminf(m, src[im * WW + jm] + c[0]); m = fminf(m, src[gi * WW + jm] + c[1]);
        m = fminf(m, src[ip * WW + jm] + c[2]); m = fminf(m, src[im * WW + gj] + c[3]);
        m = fminf(m, src[ip * WW + gj] + c[4]); m = fminf(m, src[im * WW + jp] + c[5]);
        m = fminf(m, src[gi * WW + jp] + c[6]); m = fminf(m, src[ip * WW + jp] + c[7]);
        dst[k] = m;
      }
      __syncthreads();
    }
    if (ns & 1) { for (int k = tid; k < HH * WW; k += 1024) g[k] = wsg[k]; }
    return;
  }

  // ---- setup: both LDS buffers = FINF everywhere (halo + pad), then region g_init
  for (int k = tid; k < LDH * LDW; k += 1024) { L[0][k] = FINF; L[1][k] = FINF; }
  __syncthreads();
  for (int k = tid; k < RH * RW; k += 1024) {
    const int r = k / RW, c = k - r * RW;
    const float s = start[(ri0 + r) * WW + rj0 + c];
    const float gi = fminf(fmaxf(FINF * (1.0f - s), 0.0f), FINF);
    L[0][(r + 1) * LDW + c + 4] = gi;
    L[1][(r + 1) * LDW + c + 4] = gi;
  }
  __syncthreads();

  // ---- per-thread strip (SR x SC cells), costs into registers (fully unrolled)
  const int srow = tid / SCOLS, scol = tid - (tid / SCOLS) * SCOLS;
  const bool tact = (srow < SROWS);
  const int r0 = srow * SR, c0 = scol * SC;

  float cst[SR][SC][8];
  float gr[SR][SC];
  if (tact) {
#pragma unroll
    for (int i = 0; i < SR; ++i) {
#pragma unroll
      for (int j = 0; j < SC; ++j) {
        const bool a = (r0 + i) < RH && (c0 + j) < RW;
        gr[i][j] = a ? L[0][(r0 + i + 1) * LDW + (c0 + j + 4)] : FINF;
        if (a) {
          cost8(ob, yco, xco, ri0 + r0 + i, rj0 + c0 + j, cst[i][j]);
        } else {
#pragma unroll
          for (int d = 0; d < 8; ++d) cst[i][j][d] = BIGC;  // => ng stays FINF
        }
      }
    }
  }

  // ---- leading-edge skip: strip can first change at step = Chebyshev dist to start bbox
  const int sr0b = i0 - ri0, sr1b = i1 - ri0, sc0b = j0 - rj0, sc1b = j1 - rj0;
  int rd = sr0b - (r0 + SR - 1); if (r0 - sr1b > rd) rd = r0 - sr1b; if (rd < 0) rd = 0;
  int cd = sc0b - (c0 + SC - 1); if (c0 - sc1b > cd) cd = c0 - sc1b; if (cd < 0) cd = 0;
  const int dmin = rd > cd ? rd : cd;

  const bool tN = (ri0 == 0), tS = (ri1 == HH - 1), tW = (rj0 == 0), tE = (rj1 == WW - 1);
  const bool tAny = tN || tS || tW || tE;

  for (int s = 0; s < ns; ++s) {
    const float* __restrict__ Lp = L[s & 1];
    float* __restrict__       Lq = L[(s + 1) & 1];

    // replicate-pad halo refresh (only when region touches image border; off for harness input)
    if (tAny) {
      float* Lpw = L[s & 1];
      if (tN) for (int c = tid; c < RW; c += 1024) Lpw[0 * LDW + c + 4] = Lpw[1 * LDW + c + 4];
      if (tS) for (int c = tid; c < RW; c += 1024) Lpw[(RH + 1) * LDW + c + 4] = Lpw[RH * LDW + c + 4];
      if (tW) for (int r = tid; r < RH; r += 1024) Lpw[(r + 1) * LDW + 3] = Lpw[(r + 1) * LDW + 4];
      if (tE) for (int r = tid; r < RH; r += 1024) Lpw[(r + 1) * LDW + RW + 4] = Lpw[(r + 1) * LDW + RW + 3];
      if (tid == 0) {
        if (tN && tW) Lpw[0 * LDW + 3]             = Lpw[1 * LDW + 4];
        if (tN && tE) Lpw[0 * LDW + RW + 4]        = Lpw[1 * LDW + RW + 3];
        if (tS && tW) Lpw[(RH + 1) * LDW + 3]      = Lpw[RH * LDW + 4];
        if (tS && tE) Lpw[(RH + 1) * LDW + RW + 4] = Lpw[RH * LDW + RW + 3];
      }
      __syncthreads();
    }

    const bool work = tact && (s + 1 >= dmin);
    if (work) {
      // V = (SR+2)x(SC+2) neighborhood: own rows from registers, halo rows via b128,
      // W/E edge columns via b32 reads.
      float V[SR + 2][SC + 2];
      const float4 qt = *reinterpret_cast<const float4*>(&Lp[(r0) * LDW + c0 + 4]);          // row r0-1
      const float4 qb = *reinterpret_cast<const float4*>(&Lp[(r0 + SR + 1) * LDW + c0 + 4]); // row r0+SR
      V[0][1] = qt.x; V[0][2] = qt.y; V[0][3] = qt.z; V[0][4] = qt.w;
      V[SR + 1][1] = qb.x; V[SR + 1][2] = qb.y; V[SR + 1][3] = qb.z; V[SR + 1][4] = qb.w;
#pragma unroll
      for (int i = 0; i < SR + 2; ++i) {
        V[i][0]      = Lp[(r0 + i) * LDW + c0 + 3];
        V[i][SC + 1] = Lp[(r0 + i) * LDW + c0 + 4 + SC];
      }
#pragma unroll
      for (int i = 0; i < SR; ++i)
#pragma unroll
        for (int j = 0; j < SC; ++j) V[i + 1][j + 1] = gr[i][j];

#pragma unroll
      for (int i = 0; i < SR; ++i) {
#pragma unroll
        for (int j = 0; j < SC; ++j) {
          float m = V[i + 1][j + 1];
          m = fminf(m, V[i    ][j    ] + cst[i][j][0]);
          m = fminf(m, V[i + 1][j    ] + cst[i][j][1]);
          m = fminf(m, V[i + 2][j    ] + cst[i][j][2]);
          m = fminf(m, V[i    ][j + 1] + cst[i][j][3]);
          m = fminf(m, V[i + 2][j + 1] + cst[i][j][4]);
          m = fminf(m, V[i    ][j + 2] + cst[i][j][5]);
          m = fminf(m, V[i + 1][j + 2] + cst[i][j][6]);
          m = fminf(m, V[i + 2][j + 2] + cst[i][j][7]);
          gr[i][j] = m;
        }
        // publish row to the other buffer immediately (no read-write hazard: readers use Lp)
        *reinterpret_cast<float4*>(&Lq[(r0 + i + 1) * LDW + c0 + 4]) =
            make_float4(gr[i][0], gr[i][1], gr[i][2], gr[i][3]);
      }
    }
    __syncthreads();   // one barrier per step: all Lq writes visible before next reads
  }

  // ---- write region back to g (rest of g already holds g_init from k_init)
  if (tact) {
    const bool al = ((rj0 & 3) == 0);   // c0 is a multiple of 4, so alignment is uniform
#pragma unroll
    for (int i = 0; i < SR; ++i) {
      if ((r0 + i) < RH) {
        if (al && (c0 + SC) <= RW) {
          *reinterpret_cast<float4*>(&g[(ri0 + r0 + i) * WW + rj0 + c0]) =
              make_float4(gr[i][0], gr[i][1], gr[i][2], gr[i][3]);
        } else {
#pragma unroll
          for (int j = 0; j < SC; ++j)
            if ((c0 + j) < RW) g[(ri0 + r0 + i) * WW + rj0 + c0 + j] = gr[i][j];
        }
      }
    }
  }
}

extern "C" void kernel_launch(void* const* d_in, const int* in_sizes, int n_in,
                              void* d_out, int out_size, void* d_ws, size_t ws_size,
                              hipStream_t stream)
{
  const float* ob = (const float*)d_in[0];   // obstacles [1,1,H,W]
  const float* co = (const float*)d_in[1];   // coords    [1,2,H,W] (y plane, then x plane)
  const float* st = (const float*)d_in[2];   // start_map
  // d_in[3] = goal_map: unused by the returned g
  const int* nsp  = (const int*)d_in[4];     // num_steps
  float* g = (float*)d_out;

  unsigned int* bb = (unsigned int*)d_ws;
  float* wsg = (float*)((char*)d_ws + 256);
  const int ws_ok = (ws_size >= 256 + (size_t)HH * WW * sizeof(float)) ? 1 : 0;

  k_bbinit<<<1, 64, 0, stream>>>(bb);
  k_init<<<(HH * WW / 4) / 256, 256, 0, stream>>>(st, g, bb);
  k_iter<<<1, 1024, 0, stream>>>(ob, co, st, bb, g, nsp, wsg, ws_ok);
}

// Round 3
// 159.040 us; speedup vs baseline: 4.2472x; 4.2472x over previous
//
#include <hip/hip_runtime.h>
#include <cstdint>

// DifferentiableStarPlanner, MI355X — round 3.
// Round-2 post-mortem: single-WG version spilled (VGPR_Count=64, cst[] in
// scratch -> ~750us latency-bound). Cost data (532 KB) exceeds one CU's
// register file, so spread across 16 CUs: overlapped (trapezoidal) stencil,
// 8 sub-kernels x 8 steps, halo=KS=8, no cross-block sync inside a sub-kernel.
// Exactness: min-plus update is monotone; FINF-ring errors stay >= true and
// advance <=1 cell/step inward; written tile cells are >= KS layers deep.
// Costs precomputed once into d_ws (k_cost), loaded as 2x float4 per cell.

#define HH 1024
#define WW 1024
#define FINF 1.0e7f
#define FOB  1.0e4f
#define FEPS 1e-12f
#define BIGC 1.0e30f

#define MAXR 132              // max region edge supported by tiled path (need 2*64+1=129)
#define TS   33               // tile edge (4x4 tiles cover MAXR)
#define KS   8                // steps per sub-kernel = halo width
#define NSUB 8                // KS*NSUB = 64 steps max on tiled path
#define W2   (TS + 2*KS)      // 49: working tile edge
#define LROWS 52              // LDS rows: ring(1)+working(49)+ring(1)+pad(1)
#define LSTR  60              // LDS row stride (floats)
#define SRB 2                 // strip rows/thread
#define SCB 4                 // strip cols/thread (float4 granularity)
#define NSR 25                // ceil(W2/SRB)
#define NSC 13                // ceil(W2/SCB)
#define BD  384               // block threads (>= NSR*NSC=325)

// -------- per-cell, per-direction path costs (exact port of calculateLocalPathCosts)
__device__ __forceinline__ void cost8(const float* __restrict__ ob,
                                      const float* __restrict__ yco,
                                      const float* __restrict__ xco,
                                      int gi, int gj, float c[8])
{
  const int jm = gj > 0      ? gj - 1 : 0;
  const int jp = gj < WW - 1 ? gj + 1 : WW - 1;
  const int im = gi > 0      ? gi - 1 : 0;
  const int ip = gi < HH - 1 ? gi + 1 : HH - 1;
  const float xc = xco[gi * WW + gj];
  const float yc = yco[gi * WW + gj];
  const float dl = xc - xco[gi * WW + jm]; const float l = dl * dl;
  const float dr = xc - xco[gi * WW + jp]; const float r = dr * dr;
  const float du = yc - yco[im * WW + gj]; const float u = du * du;
  const float dd = yc - yco[ip * WW + gj]; const float d = dd * dd;
  const float oc  = ob[gi * WW + gj];
  const float oNW = ob[im * WW + jm], oN = ob[im * WW + gj], oNE = ob[im * WW + jp];
  const float oE  = ob[gi * WW + jp];
  const float oSW = ob[ip * WW + jm], oS = ob[ip * WW + gj], oSE = ob[ip * WW + jp];
  // dir order: 0 NW(-1,-1) 1 W(0,-1) 2 SW(1,-1) 3 N(-1,0) 4 S(1,0) 5 NE(-1,1) 6 E(0,1) 7 SE(1,1)
  c[0] = sqrtf(l + u + FEPS) + FOB * fmaxf(oNW, oc);
  c[1] = sqrtf(l + FEPS)     + FOB * fmaxf(oN , oc);  // reference quirk: W move uses N obstacle
  c[2] = sqrtf(l + d + FEPS) + FOB * fmaxf(oSW, oc);
  c[3] = sqrtf(u + FEPS)     + FOB * fmaxf(oN , oc);
  c[4] = sqrtf(d + FEPS)     + FOB * fmaxf(oS , oc);
  c[5] = sqrtf(r + u + FEPS) + FOB * fmaxf(oNE, oc);
  c[6] = sqrtf(r + FEPS)     + FOB * fmaxf(oE , oc);
  c[7] = sqrtf(r + d + FEPS) + FOB * fmaxf(oSE, oc);
}

// region from bbox+ns, clamped to image. returns false if no start cells.
__device__ __forceinline__ bool region_of(const unsigned* __restrict__ bb, int ns,
                                          int& i0, int& i1, int& j0, int& j1,
                                          int& ri0, int& ri1, int& rj0, int& rj1,
                                          int& RH, int& RW)
{
  if (bb[0] > (unsigned)(HH - 1)) return false;
  i0 = (int)bb[0]; i1 = 4096 - (int)bb[1];
  j0 = (int)bb[2]; j1 = 4096 - (int)bb[3];
  ri0 = i0 - ns; if (ri0 < 0) ri0 = 0;
  ri1 = i1 + ns; if (ri1 > HH - 1) ri1 = HH - 1;
  rj0 = j0 - ns; if (rj0 < 0) rj0 = 0;
  rj1 = j1 + ns; if (rj1 > WW - 1) rj1 = WW - 1;
  RH = ri1 - ri0 + 1; RW = rj1 - rj0 + 1;
  return true;
}

// -------- K0: bbox init (ws re-poisoned every call)
__global__ void k_bbinit(unsigned int* bb)
{
  if (threadIdx.x < 4) bb[threadIdx.x] = 0xFFFFFFFFu;
}

// -------- K1: g_init everywhere + start bbox via atomicMin
__global__ void k_init(const float* __restrict__ start, float* __restrict__ g,
                       unsigned int* bb)
{
  const int idx = blockIdx.x * blockDim.x + threadIdx.x;     // over H*W/4
  const float4 s = reinterpret_cast<const float4*>(start)[idx];
  float4 o;
  o.x = fminf(fmaxf(FINF * (1.0f - s.x), 0.0f), FINF);
  o.y = fminf(fmaxf(FINF * (1.0f - s.y), 0.0f), FINF);
  o.z = fminf(fmaxf(FINF * (1.0f - s.z), 0.0f), FINF);
  o.w = fminf(fmaxf(FINF * (1.0f - s.w), 0.0f), FINF);
  reinterpret_cast<float4*>(g)[idx] = o;
  if (s.x > 0.0f || s.y > 0.0f || s.z > 0.0f || s.w > 0.0f) {
    const int base = idx * 4;
    const int r  = base >> 10;
    const int c0 = base & (WW - 1);
    atomicMin(bb + 0, (unsigned)r);
    atomicMin(bb + 1, (unsigned)(4096 - r));
    if (s.x > 0.0f) { atomicMin(bb + 2, (unsigned)(c0 + 0)); atomicMin(bb + 3, (unsigned)(4096 - (c0 + 0))); }
    if (s.y > 0.0f) { atomicMin(bb + 2, (unsigned)(c0 + 1)); atomicMin(bb + 3, (unsigned)(4096 - (c0 + 1))); }
    if (s.z > 0.0f) { atomicMin(bb + 2, (unsigned)(c0 + 2)); atomicMin(bb + 3, (unsigned)(4096 - (c0 + 2))); }
    if (s.w > 0.0f) { atomicMin(bb + 2, (unsigned)(c0 + 3)); atomicMin(bb + 3, (unsigned)(4096 - (c0 + 3))); }
  }
}

// -------- K2: precompute 8 costs/cell for the region into ws (region coords, AoS 2xfloat4)
__global__ void k_cost(const float* __restrict__ ob, const float* __restrict__ co,
                       const unsigned* __restrict__ bb, const int* __restrict__ nsp,
                       float* __restrict__ cw, int cost_ok)
{
  if (!cost_ok) return;
  int ns = *nsp; if (ns < 0) ns = 0;
  if (ns > KS * NSUB) return;
  int i0,i1,j0,j1, ri0,ri1,rj0,rj1, RH,RW;
  if (!region_of(bb, ns, i0,i1,j0,j1, ri0,ri1,rj0,rj1, RH,RW)) return;
  if (RH > MAXR || RW > MAXR) return;
  const int idx = blockIdx.x * blockDim.x + threadIdx.x;
  if (idx >= MAXR * MAXR) return;
  const int rr = idx / MAXR, cc = idx - rr * MAXR;
  if (rr >= RH || cc >= RW) return;
  float c8[8];
  cost8(ob, co, co + HH * WW, ri0 + rr, rj0 + cc, c8);
  float4* p = reinterpret_cast<float4*>(cw + (size_t)idx * 8);
  p[0] = make_float4(c8[0], c8[1], c8[2], c8[3]);
  p[1] = make_float4(c8[4], c8[5], c8[6], c8[7]);
}

// -------- K3 (x NSUB): one sub-kernel = KS relaxation steps on 16 overlapped tiles
__global__ __launch_bounds__(BD, 1) void k_step(
    const float* __restrict__ ob, const float* __restrict__ co,
    const unsigned* __restrict__ bb, float* __restrict__ g,
    const int* __restrict__ nsp, const float* __restrict__ cw,
    int cost_ok, int sub)
{
  __shared__ float L[2][LROWS * LSTR];
  int ns = *nsp; if (ns < 0) ns = 0;
  if (ns > KS * NSUB) return;                       // fallback path handles
  int i0,i1,j0,j1, ri0,ri1,rj0,rj1, RH,RW;
  if (!region_of(bb, ns, i0,i1,j0,j1, ri0,ri1,rj0,rj1, RH,RW)) return;
  if (RH > MAXR || RW > MAXR) return;               // fallback path handles

  const int s0 = sub * KS;
  int s1 = s0 + KS; if (s1 > ns) s1 = ns;
  const int nk = s1 - s0;
  if (nk <= 0) return;

  const int by = blockIdx.x >> 2, bx = blockIdx.x & 3;
  const int tr0 = ri0 + by * TS; if (tr0 > ri1) return;
  const int tc0 = rj0 + bx * TS; if (tc0 > rj1) return;
  const int te  = (tr0 + TS - 1 < ri1) ? tr0 + TS - 1 : ri1;
  const int tce = (tc0 + TS - 1 < rj1) ? tc0 + TS - 1 : rj1;
  // block-level leading-edge skip (Chebyshev dist of tile to start bbox)
  {
    int dr = i0 - te; if (tr0 - i1 > dr) dr = tr0 - i1; if (dr < 0) dr = 0;
    int dc = j0 - tce; if (tc0 - j1 > dc) dc = tc0 - j1; if (dc < 0) dc = 0;
    const int dminB = dr > dc ? dr : dc;
    if (dminB > s1) return;                         // tile provably all-g_init through s1
  }

  const int br = tr0 - KS, bc = tc0 - KS;           // working-tile origin (image coords)
  const int tid = threadIdx.x;

  // ---- LDS = FINF (both buffers, incl. rings and pads)
  {
    float* Lf = &L[0][0];
    for (int k = tid; k < 2 * LROWS * LSTR; k += BD) Lf[k] = FINF;
  }
  __syncthreads();

  // ---- per-thread strip: load g + costs
  const int srow = tid / NSC, scol = tid - (tid / NSC) * NSC;
  const bool act = (tid < NSR * NSC);
  const int r0 = srow * SRB, c0 = scol * SCB;

  float gr[SRB][SCB];
  float cst[SRB][SCB][8];
  if (act) {
#pragma unroll
    for (int i = 0; i < SRB; ++i) {
#pragma unroll
      for (int j = 0; j < SCB; ++j) {
        const int wi = r0 + i, wj = c0 + j;
        const int gi2 = br + wi, gj2 = bc + wj;
        const bool inw   = (wi < W2) && (wj < W2);
        const bool inimg = inw && gi2 >= 0 && gi2 < HH && gj2 >= 0 && gj2 < WW;
        float gv = FINF;
        if (inimg) gv = g[gi2 * WW + gj2];
        gr[i][j] = gv;
        const int rr = gi2 - ri0, cc = gj2 - rj0;
        const bool inreg = inimg && rr >= 0 && rr < RH && cc >= 0 && cc < RW;
        if (inreg) {
          if (cost_ok) {
            const float4* p = reinterpret_cast<const float4*>(cw + (size_t)(rr * MAXR + cc) * 8);
            const float4 a = p[0], b = p[1];
            cst[i][j][0] = a.x; cst[i][j][1] = a.y; cst[i][j][2] = a.z; cst[i][j][3] = a.w;
            cst[i][j][4] = b.x; cst[i][j][5] = b.y; cst[i][j][6] = b.z; cst[i][j][7] = b.w;
          } else {
            cost8(ob, co, co + HH * WW, gi2, gj2, cst[i][j]);
          }
        } else {
#pragma unroll
          for (int d = 0; d < 8; ++d) cst[i][j][d] = BIGC;   // keeps FINF exactly
        }
      }
      // publish loaded row into step-0 source buffer (FINF pads beyond working are correct ring values)
      *reinterpret_cast<float4*>(&L[0][(r0 + i + 1) * LSTR + c0 + 4]) =
          make_float4(gr[i][0], gr[i][1], gr[i][2], gr[i][3]);
    }
  }
  __syncthreads();

  // ---- strip-level leading-edge skip
  int ds;
  {
    const int sr = br + r0, er = br + r0 + SRB - 1;
    const int sc = bc + c0, ec = bc + c0 + SCB - 1;
    int dr = i0 - er; if (sr - i1 > dr) dr = sr - i1; if (dr < 0) dr = 0;
    int dc = j0 - ec; if (sc - j1 > dc) dc = sc - j1; if (dc < 0) dc = 0;
    ds = dr > dc ? dr : dc;
  }

  // image-border replicate flags (cold for harness input: region never near border)
  const int n0 = -br;                    // # out-of-image rows at top
  const int sLast = HH - 1 - br;         // last in-image working-row index
  const int w0 = -bc;
  const int eLast = WW - 1 - bc;
  const bool tN = (br <= 0), tS = (sLast < W2), tW = (bc <= 0), tE = (eLast < W2);
  const bool tAny = tN || tS || tW || tE;

  // ---- nk relaxation steps
  for (int t = 0; t < nk; ++t) {
    float* __restrict__ Lp = L[t & 1];
    float* __restrict__ Lq = L[(t + 1) & 1];

    if (tAny) {   // replicate-pad refresh on the buffer about to be read
      if (tN) for (int k = tid; k < (n0 + 1) * LSTR; k += BD) {
        const int r = k / LSTR, c = k - r * LSTR;
        Lp[r * LSTR + c] = Lp[(n0 + 1) * LSTR + c];
      }
      if (tS) {
        const int base = sLast + 2, cnt = 51 - base;   // rows base..50
        for (int k = tid; k < cnt * LSTR; k += BD) {
          const int r = base + k / LSTR, c = k - (k / LSTR) * LSTR;
          Lp[r * LSTR + c] = Lp[(sLast + 1) * LSTR + c];
        }
      }
      __syncthreads();
      if (tW) {
        const int cn = w0 + 1;                          // cols 3..w0+3
        for (int k = tid; k < 51 * cn; k += BD) {
          const int r = k / cn, c = 3 + (k - (k / cn) * cn);
          Lp[r * LSTR + c] = Lp[r * LSTR + w0 + 4];
        }
      }
      if (tE) {
        const int cbase = eLast + 5, cn = 56 - cbase;   // cols cbase..55
        for (int k = tid; k < 51 * cn; k += BD) {
          const int r = k / cn, c = cbase + (k - (k / cn) * cn);
          Lp[r * LSTR + c] = Lp[r * LSTR + eLast + 4];
        }
      }
      __syncthreads();
    }

    const int sg = s0 + t;
    if (act && (sg + 1 >= ds)) {
      float V[SRB + 2][SCB + 2];
      const float4 qt = *reinterpret_cast<const float4*>(&Lp[(r0) * LSTR + c0 + 4]);
      const float4 qb = *reinterpret_cast<const float4*>(&Lp[(r0 + SRB + 1) * LSTR + c0 + 4]);
      V[0][1] = qt.x; V[0][2] = qt.y; V[0][3] = qt.z; V[0][4] = qt.w;
      V[SRB + 1][1] = qb.x; V[SRB + 1][2] = qb.y; V[SRB + 1][3] = qb.z; V[SRB + 1][4] = qb.w;
#pragma unroll
      for (int i = 0; i < SRB + 2; ++i) {
        V[i][0]       = Lp[(r0 + i) * LSTR + c0 + 3];
        V[i][SCB + 1] = Lp[(r0 + i) * LSTR + c0 + 4 + SCB];
      }
#pragma unroll
      for (int i = 0; i < SRB; ++i)
#pragma unroll
        for (int j = 0; j < SCB; ++j) V[i + 1][j + 1] = gr[i][j];

#pragma unroll
      for (int i = 0; i < SRB; ++i) {
#pragma unroll
        for (int j = 0; j < SCB; ++j) {
          float m = V[i + 1][j + 1];
          m = fminf(m, V[i    ][j    ] + cst[i][j][0]);
          m = fminf(m, V[i + 1][j    ] + cst[i][j][1]);
          m = fminf(m, V[i + 2][j    ] + cst[i][j][2]);
          m = fminf(m, V[i    ][j + 1] + cst[i][j][3]);
          m = fminf(m, V[i + 2][j + 1] + cst[i][j][4]);
          m = fminf(m, V[i    ][j + 2] + cst[i][j][5]);
          m = fminf(m, V[i + 1][j + 2] + cst[i][j][6]);
          m = fminf(m, V[i + 2][j + 2] + cst[i][j][7]);
          gr[i][j] = m;
        }
        *reinterpret_cast<float4*>(&Lq[(r0 + i + 1) * LSTR + c0 + 4]) =
            make_float4(gr[i][0], gr[i][1], gr[i][2], gr[i][3]);
      }
    }
    __syncthreads();
  }

  // ---- write back tile-owned cells (>= KS layers deep => exact after nk steps)
  if (act) {
#pragma unroll
    for (int i = 0; i < SRB; ++i) {
      const int wi = r0 + i, gi2 = br + wi;
      if (wi >= KS && wi < KS + TS && gi2 <= ri1) {
#pragma unroll
        for (int j = 0; j < SCB; ++j) {
          const int wj = c0 + j, gj2 = bc + wj;
          if (wj >= KS && wj < KS + TS && gj2 <= rj1) g[gi2 * WW + gj2] = gr[i][j];
        }
      }
    }
  }
}

// -------- K4: defensive fallback (ns > 64 or huge start bbox) — no-op in harness
__global__ __launch_bounds__(1024) void k_fallback(
    const float* __restrict__ ob, const float* __restrict__ co,
    const unsigned* __restrict__ bb, float* __restrict__ g,
    const int* __restrict__ nsp, float* wsg, int ws_ok)
{
  int ns = *nsp; if (ns < 0) ns = 0;
  int i0,i1,j0,j1, ri0,ri1,rj0,rj1, RH,RW;
  if (!region_of(bb, ns, i0,i1,j0,j1, ri0,ri1,rj0,rj1, RH,RW)) return;
  if (ns <= KS * NSUB && RH <= MAXR && RW <= MAXR) return;  // tiled path did the work
  if (!ws_ok) return;
  const float* yco = co;
  const float* xco = co + HH * WW;
  const int tid = threadIdx.x;
  for (int s = 0; s < ns; ++s) {
    const float* src = (s & 1) ? wsg : g;
    float*       dst = (s & 1) ? g : wsg;
    for (int k = tid; k < HH * WW; k += 1024) {
      const int gi = k >> 10, gj = k & (WW - 1);
      float c[8]; cost8(ob, yco, xco, gi, gj, c);
      const int im = gi > 0 ? gi - 1 : 0, ip = gi < HH - 1 ? gi + 1 : HH - 1;
      const int jm = gj > 0 ? gj - 1 : 0, jp = gj < WW - 1 ? gj + 1 : WW - 1;
      float m = src[k];
      m = fminf(m, src[im * WW + jm] + c[0]); m = fminf(m, src[gi * WW + jm] + c[1]);
      m = fminf(m, src[ip * WW + jm] + c[2]); m = fminf(m, src[im * WW + gj] + c[3]);
      m = fminf(m, src[ip * WW + gj] + c[4]); m = fminf(m, src[im * WW + jp] + c[5]);
      m = fminf(m, src[gi * WW + jp] + c[6]); m = fminf(m, src[ip * WW + jp] + c[7]);
      dst[k] = m;
    }
    __syncthreads();
  }
  if (ns & 1) { for (int k = tid; k < HH * WW; k += 1024) g[k] = wsg[k]; }
}

extern "C" void kernel_launch(void* const* d_in, const int* in_sizes, int n_in,
                              void* d_out, int out_size, void* d_ws, size_t ws_size,
                              hipStream_t stream)
{
  const float* ob = (const float*)d_in[0];   // obstacles
  const float* co = (const float*)d_in[1];   // coords (y plane, x plane)
  const float* st = (const float*)d_in[2];   // start_map
  // d_in[3] = goal_map: dead w.r.t. returned g
  const int* nsp  = (const int*)d_in[4];     // num_steps
  float* g = (float*)d_out;

  unsigned int* bb = (unsigned int*)d_ws;
  const size_t costBytes = (size_t)MAXR * MAXR * 8 * sizeof(float);  // 557568
  float* cw  = (float*)((char*)d_ws + 256);
  float* wsg = (float*)((char*)d_ws + 256 + costBytes);
  const int cost_ok = (ws_size >= 256 + costBytes) ? 1 : 0;
  const int ws_ok   = (ws_size >= 256 + costBytes + (size_t)HH * WW * sizeof(float)) ? 1 : 0;

  k_bbinit<<<1, 64, 0, stream>>>(bb);
  k_init<<<(HH * WW / 4) / 256, 256, 0, stream>>>(st, g, bb);
  k_cost<<<(MAXR * MAXR + 255) / 256, 256, 0, stream>>>(ob, co, bb, nsp, cw, cost_ok);
  for (int sub = 0; sub < NSUB; ++sub)
    k_step<<<16, BD, 0, stream>>>(ob, co, bb, g, nsp, cw, cost_ok, sub);
  k_fallback<<<1, 1024, 0, stream>>>(ob, co, bb, g, nsp, wsg, ws_ok);
}